// Round 2
// baseline (274.240 us; speedup 1.0000x reference)
//
#include <hip/hip_runtime.h>
#include <hip/hip_bf16.h>

#define T_TOK 2048
#define NE 768
#define DFF 3072
#define NEXP 8
#define ROWS_PAD 4224   // 4096 pairs + 128 pad rows

typedef __attribute__((ext_vector_type(8))) __bf16 bf16x8;
typedef __attribute__((ext_vector_type(4))) float f32x4;

__device__ __forceinline__ float gelu_tanh(float v) {
  float t = tanhf(0.7978845608028654f * (v + 0.044715f * v * v * v));
  return 0.5f * v * (1.0f + t);
}

// ---------------- router: one wave per token ----------------
__global__ void router_kernel(const float* __restrict__ x,
                              const float* __restrict__ noise,
                              const float* __restrict__ rw,
                              int* __restrict__ sel, float* __restrict__ wgt,
                              int* __restrict__ cnt) {
  int tok  = (blockIdx.x * blockDim.x + threadIdx.x) >> 6;
  int lane = threadIdx.x & 63;
  const float* xr = x + (size_t)tok * NE;
  float acc[NEXP];
#pragma unroll
  for (int e = 0; e < NEXP; e++) acc[e] = 0.f;
  for (int d = lane; d < NE; d += 64) {
    float xv = xr[d];
#pragma unroll
    for (int e = 0; e < NEXP; e++) acc[e] += xv * rw[e * NE + d];
  }
#pragma unroll
  for (int e = 0; e < NEXP; e++) {
#pragma unroll
    for (int off = 32; off > 0; off >>= 1) acc[e] += __shfl_xor(acc[e], off);
  }
  if (lane == 0) {
    float lg[NEXP];
#pragma unroll
    for (int e = 0; e < NEXP; e++) lg[e] = acc[e] + noise[tok * NEXP + e];
    int i0 = 0;
#pragma unroll
    for (int e = 1; e < NEXP; e++) if (lg[e] > lg[i0]) i0 = e;
    int i1 = (i0 == 0) ? 1 : 0;
#pragma unroll
    for (int e = 0; e < NEXP; e++) if (e != i0 && lg[e] > lg[i1]) i1 = e;
    float ex = __expf(lg[i1] - lg[i0]);
    float w0 = 1.f / (1.f + ex);
    sel[tok * 2]     = i0; sel[tok * 2 + 1] = i1;
    wgt[tok * 2]     = w0; wgt[tok * 2 + 1] = 1.f - w0;
    atomicAdd(&cnt[i0], 1); atomicAdd(&cnt[i1], 1);
  }
}

// ---------------- deterministic slot assignment: 1 block, 8 waves ----------------
__global__ void assign_kernel(const int* __restrict__ sel, const float* __restrict__ wgt,
                              const int* __restrict__ cnt, int* __restrict__ offs,
                              int* __restrict__ pair_tok, float* __restrict__ pair_w) {
  __shared__ int soff[NEXP + 1];
  if (threadIdx.x == 0) {
    int s = 0;
    for (int e = 0; e < NEXP; e++) { soff[e] = s; s += cnt[e]; }
    soff[NEXP] = s;
    for (int i = 0; i <= NEXP; i++) offs[i] = soff[i];
  }
  __syncthreads();
  int e = threadIdx.x >> 6;          // 512 threads = 8 waves, wave e handles expert e
  int lane = threadIdx.x & 63;
  int base = soff[e];
  for (int t0 = 0; t0 < T_TOK; t0 += 64) {
    int t = t0 + lane;
    int s0 = sel[t * 2], s1 = sel[t * 2 + 1];
    bool m0 = (s0 == e), m1 = (s1 == e);
    bool m = m0 | m1;
    float w = m0 ? wgt[t * 2] : wgt[t * 2 + 1];
    unsigned long long mask = __ballot(m);
    int pos = __popcll(mask & ((1ull << lane) - 1ull));
    if (m) { pair_tok[base + pos] = t; pair_w[base + pos] = w; }
    base += __popcll(mask);
  }
}

// ---------------- gather x rows -> bf16, grouped by expert ----------------
__global__ void gather_kernel(const float* __restrict__ x, const int* __restrict__ pair_tok,
                              __hip_bfloat16* __restrict__ xg) {
  int r = blockIdx.x;
  int tok = pair_tok[r];
  const float* s = x + (size_t)tok * NE;
  __hip_bfloat16* d = xg + (size_t)r * NE;
  for (int i = threadIdx.x; i < NE; i += 256) d[i] = __float2bfloat16(s[i]);
}

// ---------------- fp32 [E][K][N] -> bf16 [E][N][K] (transpose + convert) ----------------
__global__ void transpose_cvt(const float* __restrict__ src, __hip_bfloat16* __restrict__ dst,
                              int K, int N) {
  __shared__ __hip_bfloat16 tile[64][66];
  int ntk = K >> 6, ntn = N >> 6;
  int bid = blockIdx.x;
  int e = bid / (ntk * ntn);
  int rem = bid % (ntk * ntn);
  int tk = rem / ntn, tn = rem % ntn;
  const float* s = src + (size_t)e * K * N + (size_t)(tk * 64) * N + tn * 64;
  int c  = threadIdx.x & 63;
  int r0 = (threadIdx.x >> 6) * 16;
  for (int i = 0; i < 16; i++)
    tile[r0 + i][c] = __float2bfloat16(s[(size_t)(r0 + i) * N + c]);
  __syncthreads();
  __hip_bfloat16* d = dst + (size_t)e * N * K + (size_t)(tn * 64) * K + tk * 64;
  int kk = threadIdx.x & 63;
  int n0 = (threadIdx.x >> 6) * 16;
  for (int i = 0; i < 16; i++)
    d[(size_t)(n0 + i) * K + kk] = tile[kk][n0 + i];
}

// ---------------- grouped GEMM, m97-structure 128x128 tile, BK=32 ----------------
// A: [rows][K] bf16 (rows grouped by expert via offs). Bt: [E][N][K] bf16.
// MODE 0: H[row][N] = bf16(gelu(acc + bias))        (GEMM1: x@w1)
// MODE 1: atomicAdd(Out[tok][col], pw*(acc + bias)) (GEMM2: h@w2, scatter)
template <int K, int N, int MODE>
__global__ __launch_bounds__(256) void ffn_gemm(
    const __hip_bfloat16* __restrict__ A, const __hip_bfloat16* __restrict__ Bt,
    const float* __restrict__ bias, __hip_bfloat16* __restrict__ H,
    float* __restrict__ Out, const int* __restrict__ offs,
    const int* __restrict__ pair_tok, const float* __restrict__ pair_w) {
  constexpr int MT_MAX = 16;           // covers up to 2048 rows per expert
  constexpr int NT = N / 128;
  int bid = blockIdx.x;
  int e = bid / (MT_MAX * NT);
  int rem = bid % (MT_MAX * NT);
  int mt = rem / NT, nt = rem % NT;
  int rbeg = offs[e], rend = offs[e + 1];
  int row0 = rbeg + mt * 128;
  if (row0 >= rend) return;
  int n0 = nt * 128;

  __shared__ __hip_bfloat16 ldsA[128 * 32];
  __shared__ __hip_bfloat16 ldsB[128 * 32];

  int tid = threadIdx.x;
  int w = tid >> 6, l = tid & 63;
  int wr = w >> 1, wc = w & 1;         // 2x2 waves -> 64x64 per wave
  int r16 = l & 15, q = l >> 4;

  f32x4 acc[4][4];
#pragma unroll
  for (int m = 0; m < 4; m++)
#pragma unroll
    for (int n = 0; n < 4; n++) acc[m][n] = (f32x4){0.f, 0.f, 0.f, 0.f};

  const __hip_bfloat16* Bte = Bt + (size_t)e * N * K;

  for (int k0 = 0; k0 < K; k0 += 32) {
#pragma unroll
    for (int i = 0; i < 2; i++) {
      int c = i * 256 + tid;           // 512 chunks of 16B per 8KB tile
      const __hip_bfloat16* ga = A + (size_t)(row0 + (c >> 2)) * K + k0 + ((c & 3) << 3);
      __builtin_amdgcn_global_load_lds(
          (const __attribute__((address_space(1))) void*)ga,
          (__attribute__((address_space(3))) void*)(&ldsA[c * 8]), 16, 0, 0);
      const __hip_bfloat16* gb = Bte + (size_t)(n0 + (c >> 2)) * K + k0 + ((c & 3) << 3);
      __builtin_amdgcn_global_load_lds(
          (const __attribute__((address_space(1))) void*)gb,
          (__attribute__((address_space(3))) void*)(&ldsB[c * 8]), 16, 0, 0);
    }
    __syncthreads();
    bf16x8 aF[4], bF[4];
#pragma unroll
    for (int m = 0; m < 4; m++)
      aF[m] = *reinterpret_cast<const bf16x8*>(&ldsA[(wr * 64 + m * 16 + r16) * 32 + q * 8]);
#pragma unroll
    for (int n = 0; n < 4; n++)
      bF[n] = *reinterpret_cast<const bf16x8*>(&ldsB[(wc * 64 + n * 16 + r16) * 32 + q * 8]);
#pragma unroll
    for (int m = 0; m < 4; m++)
#pragma unroll
      for (int n = 0; n < 4; n++)
        acc[m][n] = __builtin_amdgcn_mfma_f32_16x16x32_bf16(aF[m], bF[n], acc[m][n], 0, 0, 0);
    __syncthreads();
  }

  // epilogue: C row = row0 + wr*64 + m*16 + q*4 + reg ; col = n0 + wc*64 + n*16 + r16
#pragma unroll
  for (int m = 0; m < 4; m++) {
#pragma unroll
    for (int rg = 0; rg < 4; rg++) {
      int rr = row0 + wr * 64 + m * 16 + q * 4 + rg;
      if (rr >= rend) continue;
      int tok = 0; float pw = 0.f;
      if (MODE == 1) { tok = pair_tok[rr]; pw = pair_w[rr]; }
#pragma unroll
      for (int n = 0; n < 4; n++) {
        int col = n0 + wc * 64 + n * 16 + r16;
        float v = acc[m][n][rg] + bias[e * N + col];
        if (MODE == 0) {
          H[(size_t)rr * N + col] = __float2bfloat16(gelu_tanh(v));
        } else {
          atomicAdd(&Out[(size_t)tok * N + col], pw * v);
        }
      }
    }
  }
}

extern "C" void kernel_launch(void* const* d_in, const int* in_sizes, int n_in,
                              void* d_out, int out_size, void* d_ws, size_t ws_size,
                              hipStream_t stream) {
  const float* x     = (const float*)d_in[0];
  const float* noise = (const float*)d_in[1];
  const float* rw    = (const float*)d_in[2];
  const float* w1    = (const float*)d_in[3];
  const float* b1    = (const float*)d_in[4];
  const float* w2    = (const float*)d_in[5];
  const float* b2    = (const float*)d_in[6];
  float* out = (float*)d_out;

  char* ws = (char*)d_ws;
  size_t off = 0;
  auto carve = [&](size_t bytes) { void* p = ws + off; off = (off + bytes + 255) & ~255ull; return p; };
  int*   cnt      = (int*)carve(NEXP * 4);
  int*   offs     = (int*)carve((NEXP + 1) * 4);
  int*   sel      = (int*)carve(T_TOK * 2 * 4);
  float* wgt      = (float*)carve(T_TOK * 2 * 4);
  int*   pair_tok = (int*)carve(ROWS_PAD * 4);
  float* pair_w   = (float*)carve(ROWS_PAD * 4);
  __hip_bfloat16* xg  = (__hip_bfloat16*)carve((size_t)ROWS_PAD * NE * 2);
  __hip_bfloat16* h   = (__hip_bfloat16*)carve((size_t)ROWS_PAD * DFF * 2);
  __hip_bfloat16* wt  = (__hip_bfloat16*)carve((size_t)NEXP * NE * DFF * 2); // shared w1t/w2t

  // Defensive: if workspace is too small, leave out zeroed (diagnosable fail, not a fault/hang)
  hipMemsetAsync(d_out, 0, (size_t)out_size * sizeof(float), stream);
  if (off > ws_size) return;
  hipMemsetAsync(cnt, 0, NEXP * sizeof(int), stream);

  router_kernel<<<(T_TOK * 64) / 256, 256, 0, stream>>>(x, noise, rw, sel, wgt, cnt);
  assign_kernel<<<1, 512, 0, stream>>>(sel, wgt, cnt, offs, pair_tok, pair_w);
  gather_kernel<<<T_TOK * 2, 256, 0, stream>>>(x, pair_tok, xg);

  // w1 -> wt ([E][DFF][NE] k-contiguous), then GEMM1 (consumes wt)
  transpose_cvt<<<NEXP * (NE / 64) * (DFF / 64), 256, 0, stream>>>(w1, wt, NE, DFF);
  ffn_gemm<NE, DFF, 0><<<NEXP * 16 * (DFF / 128), 256, 0, stream>>>(
      xg, wt, b1, h, nullptr, offs, pair_tok, pair_w);

  // w2 -> wt ([E][NE][DFF] k-contiguous), then GEMM2 (stream-serialized reuse)
  transpose_cvt<<<NEXP * (DFF / 64) * (NE / 64), 256, 0, stream>>>(w2, wt, DFF, NE);
  ffn_gemm<DFF, NE, 1><<<NEXP * 16 * (NE / 128), 256, 0, stream>>>(
      h, wt, b2, nullptr, out, offs, pair_tok, pair_w);
}

// Round 3
// 271.841 us; speedup vs baseline: 1.0088x; 1.0088x over previous
//
#include <hip/hip_runtime.h>
#include <hip/hip_bf16.h>

#define T_TOK 2048
#define NE 768
#define DFF 3072
#define NEXP 8
#define ROWS_PAD 4480   // 4096 pairs + up to 255 tile-overhang + slack

typedef __attribute__((ext_vector_type(8))) __bf16 bf16x8;
typedef __attribute__((ext_vector_type(4))) __bf16 bf16x4;
typedef __attribute__((ext_vector_type(4))) float f32x4;

__device__ __forceinline__ float gelu_tanh(float v) {
  float t = tanhf(0.7978845608028654f * (v + 0.044715f * v * v * v));
  return 0.5f * v * (1.0f + t);
}

// ---------------- router: one wave per token ----------------
__global__ void router_kernel(const float* __restrict__ x,
                              const float* __restrict__ noise,
                              const float* __restrict__ rw,
                              int* __restrict__ sel, float* __restrict__ wgt,
                              int* __restrict__ cnt) {
  int tok  = (blockIdx.x * blockDim.x + threadIdx.x) >> 6;
  int lane = threadIdx.x & 63;
  const float* xr = x + (size_t)tok * NE;
  float acc[NEXP];
#pragma unroll
  for (int e = 0; e < NEXP; e++) acc[e] = 0.f;
  for (int d = lane; d < NE; d += 64) {
    float xv = xr[d];
#pragma unroll
    for (int e = 0; e < NEXP; e++) acc[e] += xv * rw[e * NE + d];
  }
#pragma unroll
  for (int e = 0; e < NEXP; e++) {
#pragma unroll
    for (int off = 32; off > 0; off >>= 1) acc[e] += __shfl_xor(acc[e], off);
  }
  if (lane == 0) {
    float lg[NEXP];
#pragma unroll
    for (int e = 0; e < NEXP; e++) lg[e] = acc[e] + noise[tok * NEXP + e];
    int i0 = 0;
#pragma unroll
    for (int e = 1; e < NEXP; e++) if (lg[e] > lg[i0]) i0 = e;
    int i1 = (i0 == 0) ? 1 : 0;
#pragma unroll
    for (int e = 0; e < NEXP; e++) if (e != i0 && lg[e] > lg[i1]) i1 = e;
    float ex = __expf(lg[i1] - lg[i0]);
    float w0 = 1.f / (1.f + ex);
    sel[tok * 2]     = i0; sel[tok * 2 + 1] = i1;
    wgt[tok * 2]     = w0; wgt[tok * 2 + 1] = 1.f - w0;
    atomicAdd(&cnt[i0], 1); atomicAdd(&cnt[i1], 1);
  }
}

// ---------------- deterministic slot assignment: 1 block, 8 waves ----------------
__global__ void assign_kernel(const int* __restrict__ sel, const float* __restrict__ wgt,
                              const int* __restrict__ cnt, int* __restrict__ offs,
                              int* __restrict__ pair_tok, float* __restrict__ pair_w) {
  __shared__ int soff[NEXP + 1];
  if (threadIdx.x == 0) {
    int s = 0;
    for (int e = 0; e < NEXP; e++) { soff[e] = s; s += cnt[e]; }
    soff[NEXP] = s;
    for (int i = 0; i <= NEXP; i++) offs[i] = soff[i];
  }
  __syncthreads();
  int e = threadIdx.x >> 6;
  int lane = threadIdx.x & 63;
  int base = soff[e];
  for (int t0 = 0; t0 < T_TOK; t0 += 64) {
    int t = t0 + lane;
    int s0 = sel[t * 2], s1 = sel[t * 2 + 1];
    bool m0 = (s0 == e), m1 = (s1 == e);
    bool m = m0 | m1;
    float w = m0 ? wgt[t * 2] : wgt[t * 2 + 1];
    unsigned long long mask = __ballot(m);
    int pos = __popcll(mask & ((1ull << lane) - 1ull));
    if (m) { pair_tok[base + pos] = t; pair_w[base + pos] = w; }
    base += __popcll(mask);
  }
}

// ---------------- gather x rows -> bf16 (vectorized) ----------------
__global__ void gather_kernel(const float* __restrict__ x, const int* __restrict__ pair_tok,
                              __hip_bfloat16* __restrict__ xg) {
  int r = blockIdx.x;
  int tok = pair_tok[r];
  const float4* s = (const float4*)(x + (size_t)tok * NE);
  __hip_bfloat16* d = xg + (size_t)r * NE;
  int t = threadIdx.x;           // 192 active threads: 192 float4 = 768 elems
  if (t < NE / 4) {
    float4 v = s[t];
    bf16x4 o;
    o[0] = (__bf16)__float2bfloat16(v.x); o[1] = (__bf16)__float2bfloat16(v.y);
    o[2] = (__bf16)__float2bfloat16(v.z); o[3] = (__bf16)__float2bfloat16(v.w);
    *reinterpret_cast<bf16x4*>(&d[t * 4]) = o;
  }
}

// ---------------- fp32 [E][K][N] -> bf16 [E][N][K], 64x64 tiles, vectorized ----------------
__global__ void transpose_cvt(const float* __restrict__ src, __hip_bfloat16* __restrict__ dst,
                              int K, int N) {
  __shared__ __hip_bfloat16 tile[64 * 72];   // [n][k], row stride 72 bf16 (144 B, 16-aligned)
  int ntk = K >> 6, ntn = N >> 6;
  int bid = blockIdx.x;
  int e = bid / (ntk * ntn);
  int rem = bid % (ntk * ntn);
  int tk = rem / ntn, tn = rem % ntn;
  const float* s = src + (size_t)e * K * N + (size_t)(tk * 64) * N + tn * 64;
  int t = threadIdx.x;
  int a = t & 15;                // n-quad: cols 4a..4a+3
  int kp = t >> 4;               // row-pair id 0..15
#pragma unroll
  for (int i = 0; i < 2; i++) {
    int k = 2 * kp + 32 * i;
    float4 v0 = *reinterpret_cast<const float4*>(&s[(size_t)k * N + 4 * a]);
    float4 v1 = *reinterpret_cast<const float4*>(&s[(size_t)(k + 1) * N + 4 * a]);
    const float* p0 = &v0.x; const float* p1 = &v1.x;
#pragma unroll
    for (int j = 0; j < 4; j++) {
      __hip_bfloat162 p;
      p.x = __float2bfloat16(p0[j]); p.y = __float2bfloat16(p1[j]);
      *reinterpret_cast<__hip_bfloat162*>(&tile[(4 * a + j) * 72 + k]) = p;
    }
  }
  __syncthreads();
  int n = t >> 2, g = t & 3;
  __hip_bfloat16* d = dst + (size_t)e * N * K + (size_t)(tn * 64 + n) * K + tk * 64;
#pragma unroll
  for (int i = 0; i < 2; i++) {
    bf16x8 v = *reinterpret_cast<const bf16x8*>(&tile[n * 72 + g * 8 + 32 * i]);
    *reinterpret_cast<bf16x8*>(&d[g * 8 + 32 * i]) = v;
  }
}

// ---------------- grouped GEMM: 256x128 tile, BK=64, 8 waves, XOR-swizzled LDS ----------------
// A: [rows][K] bf16 (expert-grouped). Bt: [E][N][K] bf16.
// MODE 0: H = bf16(gelu(acc+bias)); MODE 1: atomicAdd(Out[tok][col], pw*(acc+bias_if_sp0))
template <int K, int N, int MODE, int SPLITS>
__global__ __launch_bounds__(512) void ffn_gemm(
    const __hip_bfloat16* __restrict__ A, const __hip_bfloat16* __restrict__ Bt,
    const float* __restrict__ bias, __hip_bfloat16* __restrict__ H,
    float* __restrict__ Out, const int* __restrict__ offs,
    const int* __restrict__ pair_tok, const float* __restrict__ pair_w) {
  constexpr int MT_MAX = 8;            // 8 x 256 rows covers 2048 rows/expert
  constexpr int NT = N / 128;
  constexpr int KS = K / SPLITS;
  int bid = blockIdx.x;
  int nt = bid % NT;
  int r1 = bid / NT;
  int sp = r1 % SPLITS;
  int r2 = r1 / SPLITS;
  int mt = r2 % MT_MAX;
  int e  = r2 / MT_MAX;
  int rbeg = offs[e], rend = offs[e + 1];
  int row0 = rbeg + mt * 256;
  if (row0 >= rend) return;
  int n0 = nt * 128;
  int kbeg = sp * KS;

  __shared__ __hip_bfloat16 ldsA[256 * 64];   // [row][64k], 128 B rows, bit5^row0 swizzle
  __shared__ __hip_bfloat16 ldsB[128 * 64];

  int tid = threadIdx.x;
  int w = tid >> 6, l = tid & 63;
  int wr = w >> 1, wc = w & 1;          // 4x2 waves of 64x64
  int r16 = l & 15, q = l >> 4;

  f32x4 acc[4][4];
#pragma unroll
  for (int m = 0; m < 4; m++)
#pragma unroll
    for (int n = 0; n < 4; n++) acc[m][n] = (f32x4){0.f, 0.f, 0.f, 0.f};

  const __hip_bfloat16* Bte = Bt + (size_t)e * N * K;
  char* cA = (char*)ldsA;
  char* cB = (char*)ldsB;

  for (int k0 = kbeg; k0 < kbeg + KS; k0 += 64) {
    // ---- stage A: 2048 16B chunks; chunk c -> lds byte c*16; src col-chunk (c&7)^((row&1)<<1)
#pragma unroll
    for (int i = 0; i < 4; i++) {
      int c = tid + 512 * i;
      int row = c >> 3, j = c & 7;
      const __hip_bfloat16* ga =
          A + (size_t)(row0 + row) * K + k0 + ((j ^ ((row & 1) << 1)) << 3);
      __builtin_amdgcn_global_load_lds(
          (const __attribute__((address_space(1))) void*)ga,
          (__attribute__((address_space(3))) void*)(cA + c * 16), 16, 0, 0);
    }
    // ---- stage B: 1024 chunks
#pragma unroll
    for (int i = 0; i < 2; i++) {
      int c = tid + 512 * i;
      int row = c >> 3, j = c & 7;
      const __hip_bfloat16* gb =
          Bte + (size_t)(n0 + row) * K + k0 + ((j ^ ((row & 1) << 1)) << 3);
      __builtin_amdgcn_global_load_lds(
          (const __attribute__((address_space(1))) void*)gb,
          (__attribute__((address_space(3))) void*)(cB + c * 16), 16, 0, 0);
    }
    __syncthreads();
#pragma unroll
    for (int kk = 0; kk < 2; kk++) {
      int inner = ((kk * 64 + 16 * q) ^ ((r16 & 1) << 5));
      bf16x8 aF[4], bF[4];
#pragma unroll
      for (int m = 0; m < 4; m++)
        aF[m] = *reinterpret_cast<const bf16x8*>(cA + (wr * 64 + m * 16 + r16) * 128 + inner);
#pragma unroll
      for (int n = 0; n < 4; n++)
        bF[n] = *reinterpret_cast<const bf16x8*>(cB + (wc * 64 + n * 16 + r16) * 128 + inner);
#pragma unroll
      for (int m = 0; m < 4; m++)
#pragma unroll
        for (int n = 0; n < 4; n++)
          acc[m][n] = __builtin_amdgcn_mfma_f32_16x16x32_bf16(aF[m], bF[n], acc[m][n], 0, 0, 0);
    }
    __syncthreads();
  }

  // epilogue: row = row0 + wr*64 + m*16 + q*4 + rg ; col = n0 + wc*64 + nf*16 + r16
#pragma unroll
  for (int m = 0; m < 4; m++) {
#pragma unroll
    for (int rg = 0; rg < 4; rg++) {
      int rr = row0 + wr * 64 + m * 16 + q * 4 + rg;
      if (rr >= rend) continue;
      int tok = 0; float pw = 0.f;
      if (MODE == 1) { tok = pair_tok[rr]; pw = pair_w[rr]; }
#pragma unroll
      for (int n = 0; n < 4; n++) {
        int col = n0 + wc * 64 + n * 16 + r16;
        float v = acc[m][n][rg];
        if (MODE == 0) {
          v += bias[e * N + col];
          H[(size_t)rr * N + col] = __float2bfloat16(gelu_tanh(v));
        } else {
          if (sp == 0) v += bias[e * N + col];
          atomicAdd(&Out[(size_t)tok * N + col], pw * v);
        }
      }
    }
  }
}

extern "C" void kernel_launch(void* const* d_in, const int* in_sizes, int n_in,
                              void* d_out, int out_size, void* d_ws, size_t ws_size,
                              hipStream_t stream) {
  const float* x     = (const float*)d_in[0];
  const float* noise = (const float*)d_in[1];
  const float* rw    = (const float*)d_in[2];
  const float* w1    = (const float*)d_in[3];
  const float* b1    = (const float*)d_in[4];
  const float* w2    = (const float*)d_in[5];
  const float* b2    = (const float*)d_in[6];
  float* out = (float*)d_out;

  char* ws = (char*)d_ws;
  size_t off = 0;
  auto carve = [&](size_t bytes) { void* p = ws + off; off = (off + bytes + 255) & ~255ull; return p; };
  int*   cnt      = (int*)carve(NEXP * 4);
  int*   offs     = (int*)carve((NEXP + 1) * 4);
  int*   sel      = (int*)carve(T_TOK * 2 * 4);
  float* wgt      = (float*)carve(T_TOK * 2 * 4);
  int*   pair_tok = (int*)carve(ROWS_PAD * 4);
  float* pair_w   = (float*)carve(ROWS_PAD * 4);
  __hip_bfloat16* xg  = (__hip_bfloat16*)carve((size_t)ROWS_PAD * NE * 2);
  __hip_bfloat16* h   = (__hip_bfloat16*)carve((size_t)ROWS_PAD * DFF * 2);
  __hip_bfloat16* wt  = (__hip_bfloat16*)carve((size_t)NEXP * NE * DFF * 2); // shared w1t/w2t

  hipMemsetAsync(d_out, 0, (size_t)out_size * sizeof(float), stream);
  if (off > ws_size) return;  // diagnosable fail, not a fault
  hipMemsetAsync(cnt, 0, NEXP * sizeof(int), stream);

  router_kernel<<<(T_TOK * 64) / 256, 256, 0, stream>>>(x, noise, rw, sel, wgt, cnt);
  assign_kernel<<<1, 512, 0, stream>>>(sel, wgt, cnt, offs, pair_tok, pair_w);
  gather_kernel<<<T_TOK * 2, 256, 0, stream>>>(x, pair_tok, xg);

  // w1 [E][768][3072] -> wt [E][3072][768]; GEMM1 (no split)
  transpose_cvt<<<NEXP * (NE / 64) * (DFF / 64), 256, 0, stream>>>(w1, wt, NE, DFF);
  ffn_gemm<NE, DFF, 0, 1><<<NEXP * 8 * 1 * (DFF / 128), 512, 0, stream>>>(
      xg, wt, b1, h, nullptr, offs, pair_tok, pair_w);

  // w2 [E][3072][768] -> wt [E][768][3072]; GEMM2 (split-K x3)
  transpose_cvt<<<NEXP * (DFF / 64) * (NE / 64), 256, 0, stream>>>(w2, wt, DFF, NE);
  ffn_gemm<DFF, NE, 1, 3><<<NEXP * 8 * 3 * (NE / 128), 512, 0, stream>>>(
      h, wt, b2, nullptr, out, offs, pair_tok, pair_w);
}

// Round 4
// 264.161 us; speedup vs baseline: 1.0382x; 1.0291x over previous
//
#include <hip/hip_runtime.h>
#include <hip/hip_bf16.h>

#define T_TOK 2048
#define NE 768
#define DFF 3072
#define NEXP 8
#define ROWS_PAD 4480

typedef __attribute__((ext_vector_type(8))) __bf16 bf16x8;
typedef __attribute__((ext_vector_type(4))) __bf16 bf16x4;
typedef __attribute__((ext_vector_type(4))) float f32x4;

__device__ __forceinline__ float gelu_tanh(float v) {
  float t = tanhf(0.7978845608028654f * (v + 0.044715f * v * v * v));
  return 0.5f * v * (1.0f + t);
}

// ---------------- router: one wave per token ----------------
__global__ void router_kernel(const float* __restrict__ x,
                              const float* __restrict__ noise,
                              const float* __restrict__ rw,
                              int* __restrict__ sel, float* __restrict__ wgt,
                              int* __restrict__ cnt) {
  int tok  = (blockIdx.x * blockDim.x + threadIdx.x) >> 6;
  int lane = threadIdx.x & 63;
  const float* xr = x + (size_t)tok * NE;
  float acc[NEXP];
#pragma unroll
  for (int e = 0; e < NEXP; e++) acc[e] = 0.f;
  for (int d = lane; d < NE; d += 64) {
    float xv = xr[d];
#pragma unroll
    for (int e = 0; e < NEXP; e++) acc[e] += xv * rw[e * NE + d];
  }
#pragma unroll
  for (int e = 0; e < NEXP; e++) {
#pragma unroll
    for (int off = 32; off > 0; off >>= 1) acc[e] += __shfl_xor(acc[e], off);
  }
  if (lane == 0) {
    float lg[NEXP];
#pragma unroll
    for (int e = 0; e < NEXP; e++) lg[e] = acc[e] + noise[tok * NEXP + e];
    int i0 = 0;
#pragma unroll
    for (int e = 1; e < NEXP; e++) if (lg[e] > lg[i0]) i0 = e;
    int i1 = (i0 == 0) ? 1 : 0;
#pragma unroll
    for (int e = 0; e < NEXP; e++) if (e != i0 && lg[e] > lg[i1]) i1 = e;
    float ex = __expf(lg[i1] - lg[i0]);
    float w0 = 1.f / (1.f + ex);
    sel[tok * 2]     = i0; sel[tok * 2 + 1] = i1;
    wgt[tok * 2]     = w0; wgt[tok * 2 + 1] = 1.f - w0;
    atomicAdd(&cnt[i0], 1); atomicAdd(&cnt[i1], 1);
  }
}

// ---------------- deterministic slot assignment: 1 block, 8 waves ----------------
__global__ void assign_kernel(const int* __restrict__ sel, const float* __restrict__ wgt,
                              const int* __restrict__ cnt, int* __restrict__ offs,
                              int* __restrict__ pair_tok, float* __restrict__ pair_w) {
  __shared__ int soff[NEXP + 1];
  if (threadIdx.x == 0) {
    int s = 0;
    for (int e = 0; e < NEXP; e++) { soff[e] = s; s += cnt[e]; }
    soff[NEXP] = s;
    for (int i = 0; i <= NEXP; i++) offs[i] = soff[i];
  }
  __syncthreads();
  int e = threadIdx.x >> 6;
  int lane = threadIdx.x & 63;
  int base = soff[e];
  for (int t0 = 0; t0 < T_TOK; t0 += 64) {
    int t = t0 + lane;
    int s0 = sel[t * 2], s1 = sel[t * 2 + 1];
    bool m0 = (s0 == e), m1 = (s1 == e);
    bool m = m0 | m1;
    float w = m0 ? wgt[t * 2] : wgt[t * 2 + 1];
    unsigned long long mask = __ballot(m);
    int pos = __popcll(mask & ((1ull << lane) - 1ull));
    if (m) { pair_tok[base + pos] = t; pair_w[base + pos] = w; }
    base += __popcll(mask);
  }
}

// ---------------- gather x rows -> bf16 (vectorized) ----------------
__global__ void gather_kernel(const float* __restrict__ x, const int* __restrict__ pair_tok,
                              __hip_bfloat16* __restrict__ xg) {
  int r = blockIdx.x;
  int tok = pair_tok[r];
  const float4* s = (const float4*)(x + (size_t)tok * NE);
  __hip_bfloat16* d = xg + (size_t)r * NE;
  int t = threadIdx.x;
  if (t < NE / 4) {
    float4 v = s[t];
    bf16x4 o;
    o[0] = (__bf16)__float2bfloat16(v.x); o[1] = (__bf16)__float2bfloat16(v.y);
    o[2] = (__bf16)__float2bfloat16(v.z); o[3] = (__bf16)__float2bfloat16(v.w);
    *reinterpret_cast<bf16x4*>(&d[t * 4]) = o;
  }
}

// ---------------- fp32 [E][K][N] -> bf16 [E][N][K], 64x64 tiles, vectorized ----------------
__global__ void transpose_cvt(const float* __restrict__ src, __hip_bfloat16* __restrict__ dst,
                              int K, int N) {
  __shared__ __hip_bfloat16 tile[64 * 72];
  int ntk = K >> 6, ntn = N >> 6;
  int bid = blockIdx.x;
  int e = bid / (ntk * ntn);
  int rem = bid % (ntk * ntn);
  int tk = rem / ntn, tn = rem % ntn;
  const float* s = src + (size_t)e * K * N + (size_t)(tk * 64) * N + tn * 64;
  int t = threadIdx.x;
  int a = t & 15;
  int kp = t >> 4;
#pragma unroll
  for (int i = 0; i < 2; i++) {
    int k = 2 * kp + 32 * i;
    float4 v0 = *reinterpret_cast<const float4*>(&s[(size_t)k * N + 4 * a]);
    float4 v1 = *reinterpret_cast<const float4*>(&s[(size_t)(k + 1) * N + 4 * a]);
    const float* p0 = &v0.x; const float* p1 = &v1.x;
#pragma unroll
    for (int j = 0; j < 4; j++) {
      __hip_bfloat162 p;
      p.x = __float2bfloat16(p0[j]); p.y = __float2bfloat16(p1[j]);
      *reinterpret_cast<__hip_bfloat162*>(&tile[(4 * a + j) * 72 + k]) = p;
    }
  }
  __syncthreads();
  int n = t >> 2, g = t & 3;
  __hip_bfloat16* d = dst + (size_t)e * N * K + (size_t)(tn * 64 + n) * K + tk * 64;
#pragma unroll
  for (int i = 0; i < 2; i++) {
    bf16x8 v = *reinterpret_cast<const bf16x8*>(&tile[n * 72 + g * 8 + 32 * i]);
    *reinterpret_cast<bf16x8*>(&d[g * 8 + 32 * i]) = v;
  }
}

// ---------------- grouped GEMM: 128x128 tile, BK=64, 4 waves, row&7 chunk swizzle ----------------
// A: [rows][K] bf16 (expert-grouped). Bt: [E][N][K] bf16.
// MODE 0: H = bf16(gelu(acc+bias)); MODE 1: atomicAdd(Out[tok][col], pw*(acc+bias_if_sp0))
// LDS chunk layout: 16B chunk (row, p) holds global k-chunk (p ^ (row&7)) of that row.
template <int K, int N, int MODE, int SPLITS>
__global__ __launch_bounds__(256) void ffn_gemm(
    const __hip_bfloat16* __restrict__ A, const __hip_bfloat16* __restrict__ Bt,
    const float* __restrict__ bias, __hip_bfloat16* __restrict__ H,
    float* __restrict__ Out, const int* __restrict__ offs,
    const int* __restrict__ pair_tok, const float* __restrict__ pair_w) {
  constexpr int MT_MAX = 16;           // 16 x 128 rows covers 2048 rows/expert
  constexpr int NT = N / 128;
  constexpr int KS = K / SPLITS;
  int bid = blockIdx.x;
  int nt = bid % NT;
  int r1 = bid / NT;
  int sp = r1 % SPLITS;
  int r2 = r1 / SPLITS;
  int mt = r2 % MT_MAX;
  int e  = r2 / MT_MAX;
  int rbeg = offs[e], rend = offs[e + 1];
  int row0 = rbeg + mt * 128;
  if (row0 >= rend) return;
  int n0 = nt * 128;
  int kbeg = sp * KS;

  __shared__ __hip_bfloat16 ldsA[128 * 64];   // 16KB, rows of 128B (8 chunks)
  __shared__ __hip_bfloat16 ldsB[128 * 64];

  int tid = threadIdx.x;
  int w = tid >> 6, l = tid & 63;
  int wr = w >> 1, wc = w & 1;          // 2x2 waves of 64x64
  int r16 = l & 15, q = l >> 4;

  f32x4 acc[4][4];
#pragma unroll
  for (int m = 0; m < 4; m++)
#pragma unroll
    for (int n = 0; n < 4; n++) acc[m][n] = (f32x4){0.f, 0.f, 0.f, 0.f};

  const __hip_bfloat16* Bte = Bt + (size_t)e * N * K;
  char* cA = (char*)ldsA;
  char* cB = (char*)ldsB;
  int swz = r16 & 7;                    // row&7 for all fragment rows (m*16, w*64 keep low 3 bits)

  for (int k0 = kbeg; k0 < kbeg + KS; k0 += 64) {
    // stage: 1024 chunks each; LDS chunk c=(row,p) <- global chunk p^(row&7)
#pragma unroll
    for (int i = 0; i < 4; i++) {
      int c = tid + 256 * i;
      int row = c >> 3, p = c & 7;
      const __hip_bfloat16* ga =
          A + (size_t)(row0 + row) * K + k0 + ((p ^ (row & 7)) << 3);
      __builtin_amdgcn_global_load_lds(
          (const __attribute__((address_space(1))) void*)ga,
          (__attribute__((address_space(3))) void*)(cA + c * 16), 16, 0, 0);
    }
#pragma unroll
    for (int i = 0; i < 4; i++) {
      int c = tid + 256 * i;
      int row = c >> 3, p = c & 7;
      const __hip_bfloat16* gb =
          Bte + (size_t)(n0 + row) * K + k0 + ((p ^ (row & 7)) << 3);
      __builtin_amdgcn_global_load_lds(
          (const __attribute__((address_space(1))) void*)gb,
          (__attribute__((address_space(3))) void*)(cB + c * 16), 16, 0, 0);
    }
    __syncthreads();
#pragma unroll
    for (int kk = 0; kk < 2; kk++) {
      int inner = ((kk * 4 + q) ^ swz) << 4;   // swizzled 16B chunk within 128B row
      bf16x8 aF[4], bF[4];
#pragma unroll
      for (int m = 0; m < 4; m++)
        aF[m] = *reinterpret_cast<const bf16x8*>(cA + (wr * 64 + m * 16 + r16) * 128 + inner);
#pragma unroll
      for (int n = 0; n < 4; n++)
        bF[n] = *reinterpret_cast<const bf16x8*>(cB + (wc * 64 + n * 16 + r16) * 128 + inner);
#pragma unroll
      for (int m = 0; m < 4; m++)
#pragma unroll
        for (int n = 0; n < 4; n++)
          acc[m][n] = __builtin_amdgcn_mfma_f32_16x16x32_bf16(aF[m], bF[n], acc[m][n], 0, 0, 0);
    }
    __syncthreads();
  }

  // epilogue: row = row0 + wr*64... wait 2x2 waves on 128 rows: row = row0 + wr*64 + m*16 + q*4 + rg
#pragma unroll
  for (int m = 0; m < 4; m++) {
#pragma unroll
    for (int rg = 0; rg < 4; rg++) {
      int rr = row0 + wr * 64 + m * 16 + q * 4 + rg;
      if (rr >= rend) continue;
      int tok = 0; float pw = 0.f;
      if (MODE == 1) { tok = pair_tok[rr]; pw = pair_w[rr]; }
#pragma unroll
      for (int n = 0; n < 4; n++) {
        int col = n0 + wc * 64 + n * 16 + r16;
        float v = acc[m][n][rg];
        if (MODE == 0) {
          v += bias[e * N + col];
          H[(size_t)rr * N + col] = __float2bfloat16(gelu_tanh(v));
        } else {
          if (sp == 0) v += bias[e * N + col];
          atomicAdd(&Out[(size_t)tok * N + col], pw * v);
        }
      }
    }
  }
}

extern "C" void kernel_launch(void* const* d_in, const int* in_sizes, int n_in,
                              void* d_out, int out_size, void* d_ws, size_t ws_size,
                              hipStream_t stream) {
  const float* x     = (const float*)d_in[0];
  const float* noise = (const float*)d_in[1];
  const float* rw    = (const float*)d_in[2];
  const float* w1    = (const float*)d_in[3];
  const float* b1    = (const float*)d_in[4];
  const float* w2    = (const float*)d_in[5];
  const float* b2    = (const float*)d_in[6];
  float* out = (float*)d_out;

  char* ws = (char*)d_ws;
  size_t off = 0;
  auto carve = [&](size_t bytes) { void* p = ws + off; off = (off + bytes + 255) & ~255ull; return p; };
  int*   cnt      = (int*)carve(NEXP * 4);
  int*   offs     = (int*)carve((NEXP + 1) * 4);
  int*   sel      = (int*)carve(T_TOK * 2 * 4);
  float* wgt      = (float*)carve(T_TOK * 2 * 4);
  int*   pair_tok = (int*)carve(ROWS_PAD * 4);
  float* pair_w   = (float*)carve(ROWS_PAD * 4);
  __hip_bfloat16* xg  = (__hip_bfloat16*)carve((size_t)ROWS_PAD * NE * 2);
  __hip_bfloat16* h   = (__hip_bfloat16*)carve((size_t)ROWS_PAD * DFF * 2);
  __hip_bfloat16* wt  = (__hip_bfloat16*)carve((size_t)NEXP * NE * DFF * 2);

  hipMemsetAsync(d_out, 0, (size_t)out_size * sizeof(float), stream);
  if (off > ws_size) return;
  hipMemsetAsync(cnt, 0, NEXP * sizeof(int), stream);

  router_kernel<<<(T_TOK * 64) / 256, 256, 0, stream>>>(x, noise, rw, sel, wgt, cnt);
  assign_kernel<<<1, 512, 0, stream>>>(sel, wgt, cnt, offs, pair_tok, pair_w);
  gather_kernel<<<T_TOK * 2, 256, 0, stream>>>(x, pair_tok, xg);

  // w1 [E][768][3072] -> wt [E][3072][768]; GEMM1: K=768, N=3072, no split
  transpose_cvt<<<NEXP * (NE / 64) * (DFF / 64), 256, 0, stream>>>(w1, wt, NE, DFF);
  ffn_gemm<NE, DFF, 0, 1><<<NEXP * 16 * 1 * (DFF / 128), 256, 0, stream>>>(
      xg, wt, b1, h, nullptr, offs, pair_tok, pair_w);

  // w2 [E][3072][768] -> wt [E][768][3072]; GEMM2: K=3072, N=768, split-K x4
  transpose_cvt<<<NEXP * (DFF / 64) * (NE / 64), 256, 0, stream>>>(w2, wt, DFF, NE);
  ffn_gemm<DFF, NE, 1, 4><<<NEXP * 16 * 4 * (NE / 128), 256, 0, stream>>>(
      h, wt, b2, nullptr, out, offs, pair_tok, pair_w);
}

// Round 5
// 254.094 us; speedup vs baseline: 1.0793x; 1.0396x over previous
//
#include <hip/hip_runtime.h>
#include <hip/hip_bf16.h>

#define T_TOK 2048
#define NE 768
#define DFF 3072
#define NEXP 8
#define ROWS_PAD 4480

typedef __attribute__((ext_vector_type(8))) __bf16 bf16x8;
typedef __attribute__((ext_vector_type(4))) __bf16 bf16x4;
typedef __attribute__((ext_vector_type(4))) float f32x4;

__device__ __forceinline__ float gelu_tanh(float v) {
  float u = 0.7978845608028654f * (v + 0.044715f * v * v * v);
  float e = __expf(-2.0f * fabsf(u));
  float t = (1.0f - e) / (1.0f + e);
  t = copysignf(t, u);
  return 0.5f * v * (1.0f + t);
}

// ---------------- router: one wave per token ----------------
__global__ void router_kernel(const float* __restrict__ x,
                              const float* __restrict__ noise,
                              const float* __restrict__ rw,
                              int* __restrict__ sel, float* __restrict__ wgt,
                              int* __restrict__ cnt) {
  int tok  = (blockIdx.x * blockDim.x + threadIdx.x) >> 6;
  int lane = threadIdx.x & 63;
  const float* xr = x + (size_t)tok * NE;
  float acc[NEXP];
#pragma unroll
  for (int e = 0; e < NEXP; e++) acc[e] = 0.f;
  for (int d = lane; d < NE; d += 64) {
    float xv = xr[d];
#pragma unroll
    for (int e = 0; e < NEXP; e++) acc[e] += xv * rw[e * NE + d];
  }
#pragma unroll
  for (int e = 0; e < NEXP; e++) {
#pragma unroll
    for (int off = 32; off > 0; off >>= 1) acc[e] += __shfl_xor(acc[e], off);
  }
  if (lane == 0) {
    float lg[NEXP];
#pragma unroll
    for (int e = 0; e < NEXP; e++) lg[e] = acc[e] + noise[tok * NEXP + e];
    int i0 = 0;
#pragma unroll
    for (int e = 1; e < NEXP; e++) if (lg[e] > lg[i0]) i0 = e;
    int i1 = (i0 == 0) ? 1 : 0;
#pragma unroll
    for (int e = 0; e < NEXP; e++) if (e != i0 && lg[e] > lg[i1]) i1 = e;
    float ex = __expf(lg[i1] - lg[i0]);
    float w0 = 1.f / (1.f + ex);
    sel[tok * 2]     = i0; sel[tok * 2 + 1] = i1;
    wgt[tok * 2]     = w0; wgt[tok * 2 + 1] = 1.f - w0;
    atomicAdd(&cnt[i0], 1); atomicAdd(&cnt[i1], 1);
  }
}

// ---------------- deterministic slot assignment: 1 block, 8 waves ----------------
__global__ void assign_kernel(const int* __restrict__ sel, const float* __restrict__ wgt,
                              const int* __restrict__ cnt, int* __restrict__ offs,
                              int* __restrict__ pair_tok, float* __restrict__ pair_w) {
  __shared__ int soff[NEXP + 1];
  if (threadIdx.x == 0) {
    int s = 0;
    for (int e = 0; e < NEXP; e++) { soff[e] = s; s += cnt[e]; }
    soff[NEXP] = s;
    for (int i = 0; i <= NEXP; i++) offs[i] = soff[i];
  }
  __syncthreads();
  int e = threadIdx.x >> 6;
  int lane = threadIdx.x & 63;
  int base = soff[e];
  for (int t0 = 0; t0 < T_TOK; t0 += 64) {
    int t = t0 + lane;
    int s0 = sel[t * 2], s1 = sel[t * 2 + 1];
    bool m0 = (s0 == e), m1 = (s1 == e);
    bool m = m0 | m1;
    float w = m0 ? wgt[t * 2] : wgt[t * 2 + 1];
    unsigned long long mask = __ballot(m);
    int pos = __popcll(mask & ((1ull << lane) - 1ull));
    if (m) { pair_tok[base + pos] = t; pair_w[base + pos] = w; }
    base += __popcll(mask);
  }
}

// ---------------- gather x rows -> bf16 (vectorized) ----------------
__global__ void gather_kernel(const float* __restrict__ x, const int* __restrict__ pair_tok,
                              __hip_bfloat16* __restrict__ xg) {
  int r = blockIdx.x;
  int tok = pair_tok[r];
  const float4* s = (const float4*)(x + (size_t)tok * NE);
  __hip_bfloat16* d = xg + (size_t)r * NE;
  int t = threadIdx.x;
  if (t < NE / 4) {
    float4 v = s[t];
    bf16x4 o;
    o[0] = (__bf16)__float2bfloat16(v.x); o[1] = (__bf16)__float2bfloat16(v.y);
    o[2] = (__bf16)__float2bfloat16(v.z); o[3] = (__bf16)__float2bfloat16(v.w);
    *reinterpret_cast<bf16x4*>(&d[t * 4]) = o;
  }
}

// ---------------- fp32 [E][K][N] -> bf16 [E][N][K], 64x64 tiles ----------------
__global__ void transpose_cvt(const float* __restrict__ src, __hip_bfloat16* __restrict__ dst,
                              int K, int N) {
  __shared__ __hip_bfloat16 tile[64 * 72];
  int ntk = K >> 6, ntn = N >> 6;
  int bid = blockIdx.x;
  int e = bid / (ntk * ntn);
  int rem = bid % (ntk * ntn);
  int tk = rem / ntn, tn = rem % ntn;
  const float* s = src + (size_t)e * K * N + (size_t)(tk * 64) * N + tn * 64;
  int t = threadIdx.x;
  int a = t & 15;
  int kp = t >> 4;
#pragma unroll
  for (int i = 0; i < 2; i++) {
    int k = 2 * kp + 32 * i;
    float4 v0 = *reinterpret_cast<const float4*>(&s[(size_t)k * N + 4 * a]);
    float4 v1 = *reinterpret_cast<const float4*>(&s[(size_t)(k + 1) * N + 4 * a]);
    const float* p0 = &v0.x; const float* p1 = &v1.x;
#pragma unroll
    for (int j = 0; j < 4; j++) {
      __hip_bfloat162 p;
      p.x = __float2bfloat16(p0[j]); p.y = __float2bfloat16(p1[j]);
      *reinterpret_cast<__hip_bfloat162*>(&tile[(4 * a + j) * 72 + k]) = p;
    }
  }
  __syncthreads();
  // write: 8 lanes per row -> full 128B global segments per wave
  int n = t >> 3, g = t & 7;
  __hip_bfloat16* d = dst + (size_t)e * N * K + (size_t)(tn * 64) * K + tk * 64;
#pragma unroll
  for (int i = 0; i < 2; i++) {
    int row = n + 32 * i;
    bf16x8 v = *reinterpret_cast<const bf16x8*>(&tile[row * 72 + g * 8]);
    *reinterpret_cast<bf16x8*>(&d[(size_t)row * K + g * 8]) = v;
  }
}

// ---------------- grouped GEMM: 256x256 tile, BK=64, 8 waves, dbuf prefetch ----------------
// A: [rows][K] bf16 (expert-grouped). Bt: [E][N][K] bf16 (k-contiguous).
// bid = widx*8 + e  (expert -> XCD affinity under %8 round-robin dispatch)
// MODE 0: H = bf16(gelu(acc+bias)); MODE 1: atomicAdd(Out[tok][col], pw*(acc+bias_if_sp0))
template <int K, int N, int MODE, int SPLITS>
__global__ __launch_bounds__(512, 1) void ffn_gemm(
    const __hip_bfloat16* __restrict__ A, const __hip_bfloat16* __restrict__ Bt,
    const float* __restrict__ bias, __hip_bfloat16* __restrict__ H,
    float* __restrict__ Out, const int* __restrict__ offs,
    const int* __restrict__ pair_tok, const float* __restrict__ pair_w) {
  constexpr int MT_MAX = 8;            // 8 x 256 rows covers 2048 rows/expert
  constexpr int NT = N / 256;
  constexpr int KS = K / SPLITS;
  constexpr int NSTAGE = KS / 64;

  int bid = blockIdx.x;
  int e = bid & 7;
  int widx = bid >> 3;
  int nt = widx % NT;
  int r1 = widx / NT;
  int sp = r1 % SPLITS;
  int mt = r1 / SPLITS;
  int rbeg = offs[e], rend = offs[e + 1];
  int row0 = rbeg + mt * 256;
  if (row0 >= rend) return;
  int n0 = nt * 256;
  int kbeg = sp * KS;

  // 2 buffers x (A 32KB + B 32KB) = 128 KB
  __shared__ __hip_bfloat16 lds[2][2][256 * 64];

  int tid = threadIdx.x;
  int w = tid >> 6, l = tid & 63;
  int wr = w >> 2, wc = w & 3;          // 2x4 waves; wave tile 128 rows x 64 cols
  int r16 = l & 15, q = l >> 4;
  int swz = r16 & 7;

  f32x4 acc[8][4];
#pragma unroll
  for (int m = 0; m < 8; m++)
#pragma unroll
    for (int n = 0; n < 4; n++) acc[m][n] = (f32x4){0.f, 0.f, 0.f, 0.f};

  const __hip_bfloat16* Bte = Bt + (size_t)e * N * K;

  // stage one 64-wide K slice of A(256 rows) + B(256 cols) into buffer b
  auto STAGE = [&](int b, int k0) {
    char* cA = (char*)lds[b][0];
    char* cB = (char*)lds[b][1];
#pragma unroll
    for (int i = 0; i < 4; i++) {
      int c = tid + 512 * i;            // 2048 chunks of 16B
      int row = c >> 3, p = c & 7;
      const __hip_bfloat16* ga =
          A + (size_t)(row0 + row) * K + k0 + ((p ^ (row & 7)) << 3);
      __builtin_amdgcn_global_load_lds(
          (const __attribute__((address_space(1))) void*)ga,
          (__attribute__((address_space(3))) void*)(cA + c * 16), 16, 0, 0);
    }
#pragma unroll
    for (int i = 0; i < 4; i++) {
      int c = tid + 512 * i;
      int row = c >> 3, p = c & 7;
      const __hip_bfloat16* gb =
          Bte + (size_t)(n0 + row) * K + k0 + ((p ^ (row & 7)) << 3);
      __builtin_amdgcn_global_load_lds(
          (const __attribute__((address_space(1))) void*)gb,
          (__attribute__((address_space(3))) void*)(cB + c * 16), 16, 0, 0);
    }
  };

  STAGE(0, kbeg);
  __syncthreads();
  int cur = 0;
  for (int t = 0; t < NSTAGE; t++) {
    if (t + 1 < NSTAGE) STAGE(cur ^ 1, kbeg + (t + 1) * 64);  // prefetch next
    const char* cA = (const char*)lds[cur][0];
    const char* cB = (const char*)lds[cur][1];
#pragma unroll
    for (int kk = 0; kk < 2; kk++) {
      int inner = ((kk * 4 + q) ^ swz) << 4;
      bf16x8 aF[8], bF[4];
#pragma unroll
      for (int m = 0; m < 8; m++)
        aF[m] = *reinterpret_cast<const bf16x8*>(cA + (wr * 128 + m * 16 + r16) * 128 + inner);
#pragma unroll
      for (int n = 0; n < 4; n++)
        bF[n] = *reinterpret_cast<const bf16x8*>(cB + (wc * 64 + n * 16 + r16) * 128 + inner);
#pragma unroll
      for (int m = 0; m < 8; m++)
#pragma unroll
        for (int n = 0; n < 4; n++)
          acc[m][n] = __builtin_amdgcn_mfma_f32_16x16x32_bf16(aF[m], bF[n], acc[m][n], 0, 0, 0);
    }
    if (t + 1 < NSTAGE) __syncthreads();   // next buffer staged AND this buffer fully read
    cur ^= 1;
  }

  // epilogue: row = row0 + wr*128 + m*16 + q*4 + rg ; col = n0 + wc*64 + n*16 + r16
#pragma unroll
  for (int m = 0; m < 8; m++) {
#pragma unroll
    for (int rg = 0; rg < 4; rg++) {
      int rr = row0 + wr * 128 + m * 16 + q * 4 + rg;
      if (rr >= rend) continue;
      int tok = 0; float pw = 0.f;
      if (MODE == 1) { tok = pair_tok[rr]; pw = pair_w[rr]; }
#pragma unroll
      for (int n = 0; n < 4; n++) {
        int col = n0 + wc * 64 + n * 16 + r16;
        float v = acc[m][n][rg];
        if (MODE == 0) {
          v += bias[e * N + col];
          H[(size_t)rr * N + col] = __float2bfloat16(gelu_tanh(v));
        } else {
          if (sp == 0) v += bias[e * N + col];
          atomicAdd(&Out[(size_t)tok * N + col], pw * v);
        }
      }
    }
  }
}

extern "C" void kernel_launch(void* const* d_in, const int* in_sizes, int n_in,
                              void* d_out, int out_size, void* d_ws, size_t ws_size,
                              hipStream_t stream) {
  const float* x     = (const float*)d_in[0];
  const float* noise = (const float*)d_in[1];
  const float* rw    = (const float*)d_in[2];
  const float* w1    = (const float*)d_in[3];
  const float* b1    = (const float*)d_in[4];
  const float* w2    = (const float*)d_in[5];
  const float* b2    = (const float*)d_in[6];
  float* out = (float*)d_out;

  char* ws = (char*)d_ws;
  size_t off = 0;
  auto carve = [&](size_t bytes) { void* p = ws + off; off = (off + bytes + 255) & ~255ull; return p; };
  int*   cnt      = (int*)carve(NEXP * 4);
  int*   offs     = (int*)carve((NEXP + 1) * 4);
  int*   sel      = (int*)carve(T_TOK * 2 * 4);
  float* wgt      = (float*)carve(T_TOK * 2 * 4);
  int*   pair_tok = (int*)carve(ROWS_PAD * 4);
  float* pair_w   = (float*)carve(ROWS_PAD * 4);
  __hip_bfloat16* xg  = (__hip_bfloat16*)carve((size_t)ROWS_PAD * NE * 2);
  __hip_bfloat16* h   = (__hip_bfloat16*)carve((size_t)ROWS_PAD * DFF * 2);
  __hip_bfloat16* wt  = (__hip_bfloat16*)carve((size_t)NEXP * NE * DFF * 2);

  hipMemsetAsync(d_out, 0, (size_t)out_size * sizeof(float), stream);
  if (off > ws_size) return;
  hipMemsetAsync(cnt, 0, NEXP * sizeof(int), stream);

  router_kernel<<<(T_TOK * 64) / 256, 256, 0, stream>>>(x, noise, rw, sel, wgt, cnt);
  assign_kernel<<<1, 512, 0, stream>>>(sel, wgt, cnt, offs, pair_tok, pair_w);
  gather_kernel<<<T_TOK * 2, 256, 0, stream>>>(x, pair_tok, xg);

  // w1 [E][768][3072] -> wt [E][3072][768]; GEMM1: K=768, N=3072
  transpose_cvt<<<NEXP * (NE / 64) * (DFF / 64), 256, 0, stream>>>(w1, wt, NE, DFF);
  ffn_gemm<NE, DFF, 0, 1><<<NEXP * 8 * 1 * (DFF / 256), 512, 0, stream>>>(
      xg, wt, b1, h, nullptr, offs, pair_tok, pair_w);

  // w2 [E][3072][768] -> wt [E][768][3072]; GEMM2: K=3072, N=768, split-K x4
  transpose_cvt<<<NEXP * (DFF / 64) * (NE / 64), 256, 0, stream>>>(w2, wt, DFF, NE);
  ffn_gemm<DFF, NE, 1, 4><<<NEXP * 8 * 4 * (NE / 256), 512, 0, stream>>>(
      h, wt, b2, nullptr, out, offs, pair_tok, pair_w);
}